// Round 7
// baseline (178.469 us; speedup 1.0000x reference)
//
#include <hip/hip_runtime.h>
#include <stdint.h>

#define GK 2048
#define GN 2048
#define GM 8192  // tokens = 4 * 2048

#define NVX (GM * (unsigned)GK / 4)   // 4,194,304 float4 in x
#define NVW (GN * (unsigned)GK / 4)   // 1,048,576 float4 in w

#define XBLK 1024  // absmax x-blocks: 16 iters exactly
#define WBLK 256   // absmax w-blocks: 16 iters exactly
#define QXBLK 4096 // quant x-blocks: 4 float4/thread exactly
#define QWBLK 1024 // quant w-blocks
#define NT (GK / 128)  // 16 K-tiles

typedef int i32x4 __attribute__((ext_vector_type(4)));

__device__ __forceinline__ float amax4(float4 v) {
    return fmaxf(fmaxf(fabsf(v.x), fabsf(v.y)), fmaxf(fabsf(v.z), fabsf(v.w)));
}

// ---------------------------------------------------------------------------
// Stage 1: per-block absmax partials (ILP-4, no atomics, no inner branch)
// ---------------------------------------------------------------------------
__global__ __launch_bounds__(256) void absmax_kernel(
    const float4* __restrict__ xv, const float4* __restrict__ wv,
    float* __restrict__ partial)
{
    const bool isx = blockIdx.x < XBLK;
    const float4* __restrict__ src = isx ? xv : wv;
    const unsigned n      = isx ? NVX : NVW;
    const unsigned b0     = isx ? blockIdx.x : blockIdx.x - XBLK;
    const unsigned stride = (isx ? XBLK : WBLK) * 256u;

    unsigned i = b0 * 256u + threadIdx.x;
    float m = 0.f;
    for (; i + 3u * stride < n; i += 4u * stride) {
        float4 a = src[i];
        float4 b = src[i + stride];
        float4 c = src[i + 2u * stride];
        float4 d = src[i + 3u * stride];
        m = fmaxf(m, fmaxf(fmaxf(amax4(a), amax4(b)),
                           fmaxf(amax4(c), amax4(d))));
    }
    for (; i < n; i += stride) m = fmaxf(m, amax4(src[i]));

    #pragma unroll
    for (int off = 32; off > 0; off >>= 1)
        m = fmaxf(m, __shfl_xor(m, off, 64));

    __shared__ float sm[4];
    const int wid = threadIdx.x >> 6;
    if ((threadIdx.x & 63) == 0) sm[wid] = m;
    __syncthreads();
    if (threadIdx.x == 0)
        partial[blockIdx.x] = fmaxf(fmaxf(sm[0], sm[1]), fmaxf(sm[2], sm[3]));
}

// ---------------------------------------------------------------------------
// Block-local reduce of the 1280 partials (x: [0,1024), w: [1024,1280)).
// ---------------------------------------------------------------------------
__device__ __forceinline__ void reduce_scales(const float* __restrict__ partial,
                                              int tid, float* ax_out, float* aw_out)
{
    __shared__ float smx[4], smw[4];
    float mx = 0.f, mw = 0.f;
    if (tid < 256) {
        mx = fmaxf(fmaxf(partial[tid], partial[tid + 256]),
                   fmaxf(partial[tid + 512], partial[tid + 768]));
        mw = partial[1024 + tid];
        #pragma unroll
        for (int off = 32; off > 0; off >>= 1) {
            mx = fmaxf(mx, __shfl_xor(mx, off, 64));
            mw = fmaxf(mw, __shfl_xor(mw, off, 64));
        }
        if ((tid & 63) == 0) { smx[tid >> 6] = mx; smw[tid >> 6] = mw; }
    }
    __syncthreads();
    *ax_out = fmaxf(fmaxf(smx[0], smx[1]), fmaxf(smx[2], smx[3]));
    *aw_out = fmaxf(fmaxf(smw[0], smw[1]), fmaxf(smw[2], smw[3]));
}

// ---------------------------------------------------------------------------
// Stage 2: quantize. Bit-exact: q = rintf(v / (absmax/127)), half-even,
// IEEE div, clip, cast. ILP-4, unit-stride loads and stores.
// ---------------------------------------------------------------------------
__device__ __forceinline__ signed char quant1(float v, float s) {
    float r = rintf(v / s);
    r = fminf(fmaxf(r, -128.f), 127.f);
    return (signed char)(int)r;
}

__device__ __forceinline__ char4 quantv(float4 v, float s) {
    char4 q;
    q.x = quant1(v.x, s); q.y = quant1(v.y, s);
    q.z = quant1(v.z, s); q.w = quant1(v.w, s);
    return q;
}

__global__ __launch_bounds__(256) void quant_kernel(
    const float4* __restrict__ xv, const float4* __restrict__ wv,
    const float* __restrict__ partial,
    char4* __restrict__ xq, char4* __restrict__ wq)
{
    float ax, aw;
    reduce_scales(partial, threadIdx.x, &ax, &aw);

    const bool isx = blockIdx.x < QXBLK;
    const float s = (isx ? ax : aw) / 127.0f;
    const float4* __restrict__ src = isx ? xv : wv;
    char4* __restrict__ dst        = isx ? xq : wq;
    const unsigned b0     = isx ? blockIdx.x : blockIdx.x - QXBLK;
    const unsigned stride = (isx ? QXBLK : QWBLK) * 256u;
    const unsigned t      = b0 * 256u + threadIdx.x;

    float4 a = src[t];
    float4 b = src[t + stride];
    float4 c = src[t + 2u * stride];
    float4 d = src[t + 3u * stride];
    dst[t]               = quantv(a, s);
    dst[t + stride]      = quantv(b, s);
    dst[t + 2u * stride] = quantv(c, s);
    dst[t + 3u * stride] = quantv(d, s);
}

// ---------------------------------------------------------------------------
// Stage 3: int8 GEMM — 256x256 tile, BK=128, 8 waves (2M x 4N), FLUID
// schedule: ONE s_barrier + ONE vmcnt(0) per K-tile, no intra-tile barriers.
// All 8 stage-issues for tile t+1 go at the TOP of tile t's body (pinned by
// sched_barrier), so the vmcnt(0) at the bottom waits on ~2600-cycle-old
// loads (>> 900cy HBM latency) — near-free. ds_reads and MFMAs flow freely;
// compiler's fine-grained lgkmcnt + 2 waves/SIMD overlap LDS (~2300 cyc/tile)
// under MFMA (~2600 cyc/tile).
// Correctness of the single collective barrier per tile:
//  (a) stage(t+1)->nbuf vs reads(t-1) of same buffer: end-of-(t-1) barrier is
//      collective -> all waves done reading before any wave stages.
//  (b) reads(t+1) vs stage(t+1): each wave drains its OWN stages (vmcnt(0))
//      before the end-of-t barrier -> transitively visible to all waves.
// LDS 128KB dbuf, XOR swizzle via pre-swizzled source (conflict-free, R3+),
// mfma_i32_16x16x64_i8, T1 bijective XCD swizzle, fused dequant+bias.
// A = xq [M,K] rm; B = wq [N,K] rm (weight [out,in] = B^T).
// ---------------------------------------------------------------------------
__global__ __launch_bounds__(512, 2) void gemm_kernel(
    const signed char* __restrict__ Aq,
    const signed char* __restrict__ Bq,
    const float* __restrict__ bias,
    const float* __restrict__ partial,
    float* __restrict__ out)
{
    __shared__ signed char lds[131072];   // [2 bufs][A 32KB | B 32KB]

    const int tid  = threadIdx.x;
    const int lane = tid & 63;
    const int wid  = tid >> 6;       // 0..7
    const int wr   = wid >> 2;       // 0..1  -> M rows [wr*128, +128)
    const int wc   = wid & 3;        // 0..3  -> N cols [wc*64, +64)

    // T1 bijective XCD swizzle: 256 blocks, 8 XCDs, 32 consecutive wgids/XCD
    const int wgid = ((blockIdx.x & 7) << 5) | (blockIdx.x >> 3);
    const int bn   = wgid & 7;       // GN/256 = 8
    const int bm   = wgid >> 3;      // GM/256 = 32

    float ax, aw;
    reduce_scales(partial, tid, &ax, &aw);
    const float s = (ax / 127.0f) * (aw / 127.0f);

    // ---- staging: 8 issues/thread/tile (A:4, B:4), 16B each ----
    const int srcslot = (tid & 7) ^ ((tid >> 3) & 7);   // pre-swizzled source
    const signed char* aSrc[4]; const signed char* bSrc[4];
    int aDst[4], bDst[4];
    #pragma unroll
    for (int he = 0; he < 4; ++he) {
        const int h = he >> 1, e = he & 1;
        const int r = h * 128 + e * 64 + (tid >> 3);
        aSrc[he] = Aq + (long)(bm * 256 + r) * GK + srcslot * 16;
        bSrc[he] = Bq + (long)(bn * 256 + r) * GK + srcslot * 16;
        aDst[he] = h * 16384 + e * 8192 + tid * 16;
        bDst[he] = 32768 + h * 16384 + e * 8192 + tid * 16;
    }

    #define STAGE_ALL(buf, koff)                                               \
        { _Pragma("unroll")                                                    \
          for (int he = 0; he < 4; ++he) {                                     \
            __builtin_amdgcn_global_load_lds(                                  \
              (const __attribute__((address_space(1))) void*)(aSrc[he] + (koff)),       \
              (__attribute__((address_space(3))) void*)((buf) + aDst[he]), 16, 0, 0);   \
            __builtin_amdgcn_global_load_lds(                                  \
              (const __attribute__((address_space(1))) void*)(bSrc[he] + (koff)),       \
              (__attribute__((address_space(3))) void*)((buf) + bDst[he]), 16, 0, 0);   \
          } }

    // ---- ds_read constants: frag row = base + 16*idx + (lane&15) ----
    const int lcol = lane & 15;
    const int g0   = lane >> 4;          // k-subslot 0..3
    const int r7   = lcol & 7;
    int aOff[8], bOff[4];
    #pragma unroll
    for (int m = 0; m < 8; ++m) aOff[m] = (wr * 128 + m * 16 + lcol) * 128;
    #pragma unroll
    for (int n = 0; n < 4; ++n) bOff[n] = 32768 + (wc * 64 + n * 16 + lcol) * 128;

    i32x4 acc[8][4] = {};

    // ---- prologue: stage tile 0 into buf 0, drain once ----
    STAGE_ALL(lds, 0)
    __syncthreads();   // vmcnt(0) drain + barrier (one-time)

    // ---- K loop: fluid body, 1 barrier + 1 (old) vmcnt(0) per tile ----
    for (int t = 0; t < NT; ++t) {
        const signed char* buf = lds + (t & 1) * 65536;
        signed char* nbuf      = lds + ((t & 1) ^ 1) * 65536;

        // 1) issue next tile's stages FIRST (matures during this tile's math)
        if (t + 1 < NT) STAGE_ALL(nbuf, (long)(t + 1) * 128)
        __builtin_amdgcn_sched_barrier(0);   // pin stage issues at tile top

        // 2) compute: reads and MFMAs flow; compiler emits counted lgkmcnt
        #pragma unroll
        for (int ks = 0; ks < 2; ++ks) {
            const int sw = ((ks * 4 + g0) ^ r7) << 4;   // swizzled 16B slot
            i32x4 bf[4];
            #pragma unroll
            for (int n = 0; n < 4; ++n)
                bf[n] = *(const i32x4*)(buf + bOff[n] + sw);
            #pragma unroll
            for (int m = 0; m < 8; ++m) {
                const i32x4 af = *(const i32x4*)(buf + aOff[m] + sw);
                #pragma unroll
                for (int n = 0; n < 4; ++n)
                    acc[m][n] = __builtin_amdgcn_mfma_i32_16x16x64_i8(
                        af, bf[n], acc[m][n], 0, 0, 0);
            }
        }

        // 3) drain own stages (issued ~2600 cyc ago -> cheap), then collective
        //    barrier publishes them and closes this tile's reads.
        asm volatile("s_waitcnt vmcnt(0)" ::: "memory");
        __builtin_amdgcn_sched_barrier(0);
        __builtin_amdgcn_s_barrier();
    }

    // ---- epilogue: dequant + bias. C/D: col=lane&15, row=(lane>>4)*4+reg ----
    const int orow0 = bm * 256 + wr * 128 + (lane >> 4) * 4;
    const int ocol0 = bn * 256 + wc * 64 + lcol;
    #pragma unroll
    for (int n = 0; n < 4; ++n) {
        const int col = ocol0 + n * 16;
        const float bv = bias[col];
        #pragma unroll
        for (int m = 0; m < 8; ++m) {
            const int row = orow0 + m * 16;
            #pragma unroll
            for (int i = 0; i < 4; ++i)
                out[(long)(row + i) * GN + col] = (float)acc[m][n][i] * s + bv;
        }
    }
    #undef STAGE_ALL
}

// ---------------------------------------------------------------------------
extern "C" void kernel_launch(void* const* d_in, const int* in_sizes, int n_in,
                              void* d_out, int out_size, void* d_ws, size_t ws_size,
                              hipStream_t stream) {
    const float* x    = (const float*)d_in[0];
    const float* w    = (const float*)d_in[1];
    const float* bias = (const float*)d_in[2];
    float* out = (float*)d_out;

    const size_t need = 8192 + (size_t)GM * GK + (size_t)GN * GK;
    if (ws_size < need) return;

    float* partial   = (float*)d_ws + 4;
    signed char* xq  = (signed char*)d_ws + 8192;
    signed char* wq  = xq + (size_t)GM * GK;

    absmax_kernel<<<XBLK + WBLK, 256, 0, stream>>>(
        (const float4*)x, (const float4*)w, partial);
    quant_kernel<<<QXBLK + QWBLK, 256, 0, stream>>>(
        (const float4*)x, (const float4*)w, partial, (char4*)xq, (char4*)wq);
    gemm_kernel<<<(GM / 256) * (GN / 256), 512, 0, stream>>>(
        xq, wq, bias, partial, out);
}